// Round 12
// baseline (90.642 us; speedup 1.0000x reference)
//
#include <hip/hip_runtime.h>
#include <math.h>

#define NIMG 24        // B*C = 8*3
#define H    256
#define W    256
#define NPIX (H * W)
#define SLICES 32                 // blocks per image (8 rows / 8 cols each)
#define NBLK (NIMG * SLICES)      // 768 blocks
#define BLKT 256
#define CPB  8                    // columns per phase-B tile
#define LDP  9                    // padded LDS row stride
#define BIGI 1000000
#define CAPTHR (-5.0e5f)          // f below this => row-has-no-foreground marker

// ---------------------------------------------------------------------------
// ONE compute kernel + one 1.6KB memset node (r11 lesson: ~16us of the 25.6
// was inter-node drain/launch structure, not work).
// Block = (img, grp). Phase A: ballot-based O(1) row EDT (r11-validated,
// bit-exact) for the block's OWN 8 rows -> coalesced f stores. Pred tile
// staged to LDS before the barrier (overlaps the wait). Per-image 32-block
// spin barrier (64B-padded counters, memset-initialized; release fence +
// relaxed agent-scope polls + acquire fence — the cross-XCD discipline that
// r7's grid.sync validated, without its full-grid convoy). Deadlock-free by
// full residency: 3 blocks/CU (12 waves, 18.5KB LDS, VGPR<<128) => all 768
// blocks resident regardless of dispatch order.
// Phase B: r11's window-bounded exact min-plus (minimizer satisfies
// |i-k| <= g[i]; all finite terms exact fp32 ints -> bitwise equal to
// reference), + sigmoid*d, fixed-order double reduction.
// Ticket finalize: ticket memset to 0 each replay (r8 lesson: poisoned-start
// tickets are unsound) -> old==NBLK-1 is truly the LAST arriver; winner
// acquires and reduces 768 partials in fixed order -> deterministic.
// ---------------------------------------------------------------------------
__global__ __launch_bounds__(BLKT)
void boundary_fused_kernel(const int* __restrict__ tgt,
                           const float* __restrict__ pred,
                           float* __restrict__ fbuf,
                           double* __restrict__ partials,
                           unsigned int* __restrict__ syncw,
                           float* __restrict__ out) {
    const int bid  = blockIdx.x;
    const int img  = bid >> 5;
    const int grp  = bid & 31;         // row-slice id AND column-group id
    const int j0   = grp << 3;
    const int t    = threadIdx.x;
    const int lane = t & 63;
    const int wid  = t >> 6;

    __shared__ float sf[H][LDP];       // 9.2 KB f tile
    __shared__ float sp[H][LDP];       // 9.2 KB pred tile
    __shared__ double wsum[4];
    __shared__ int nonempty, won;
    if (t == 0) nonempty = 0;

    // ---------- phase A: row EDT for my 8 rows (ballot O(1), bit-exact) ----
#pragma unroll
    for (int s = 0; s < 2; ++s) {
        const int row = (grp << 3) + (wid << 1) + s;
        const int4 tv = ((const int4*)(tgt + (img << 16) + (row << 8)))[lane];
        const int c0 = lane << 2;

        const int prevw = __shfl_up(tv.w, 1, 64);
        const bool ch0 = (lane > 0) && ((tv.x != 0) != (prevw != 0));
        const bool ch1 = (tv.y != 0) != (tv.x != 0);
        const bool ch2 = (tv.z != 0) != (tv.y != 0);
        const bool ch3 = (tv.w != 0) != (tv.z != 0);

        const int a0 = ch0 ? c0     : -BIGI;
        const int a1 = ch1 ? c0 + 1 : a0;
        const int a2 = ch2 ? c0 + 2 : a1;
        const int a3 = ch3 ? c0 + 3 : a2;     // lane's last change (or -BIGI)
        const int rb3 = ch3 ? c0 + 3 : BIGI;
        const int rb2 = ch2 ? c0 + 2 : rb3;
        const int rb1 = ch1 ? c0 + 1 : rb2;
        const int rb0 = ch0 ? c0     : rb1;   // lane's first change (or BIGI)

        const unsigned long long mask = __ballot(ch0 | ch1 | ch2 | ch3);
        const unsigned long long lowm = mask & ((1ULL << lane) - 1ULL);
        const unsigned long long him  = (lane < 63) ? (mask >> (lane + 1)) : 0ULL;

        const int plane = 63 - __builtin_clzll(lowm | 1ULL);
        const int sh_a  = __shfl(a3, plane & 63, 64);
        const int ex    = (lowm != 0ULL) ? sh_a : -BIGI;   // last change < c0

        const int qlane = lane + 1 +
            (int)__builtin_ctzll(him | 0x8000000000000000ULL);
        const int sh_r  = __shfl(rb0, qlane & 63, 64);
        const int exr   = (him != 0ULL) ? sh_r : BIGI;     // first change > c3

        const int s0 = (ex > a0) ? ex : a0;
        const int s1 = (ex > a1) ? ex : a1;
        const int s2 = (ex > a2) ? ex : a2;
        const int s3 = (ex > a3) ? ex : a3;
        const int n0 = (rb1 < exr) ? rb1 : exr;
        const int n1 = (rb2 < exr) ? rb2 : exr;
        const int n2 = (rb3 < exr) ? rb3 : exr;
        const int n3 = exr;

        auto gcalc = [](int c, int ss, int nn) -> int {
            int dp = c - ss + 1;
            int dn = nn - c;
            int g = dp < dn ? dp : dn;
            return g < BIGI ? g : BIGI;
        };
        const float g0 = (float)gcalc(c0,     s0, n0);
        const float g1 = (float)gcalc(c0 + 1, s1, n1);
        const float g2 = (float)gcalc(c0 + 2, s2, n2);
        const float g3 = (float)gcalc(c0 + 3, s3, n3);

        float4 o;
        o.x = (tv.x != 0) ? g0 : -g0;
        o.y = (tv.y != 0) ? g1 : -g1;
        o.z = (tv.z != 0) ? g2 : -g2;
        o.w = (tv.w != 0) ? g3 : -g3;
        ((float4*)(fbuf + (img << 16) + (row << 8)))[lane] = o;
    }

    // ---------- stage pred tile (independent of f; overlaps barrier) ------
#pragma unroll
    for (int s = 0; s < 2; ++s) {
        const int id  = t + (s << 8);
        const int row = id >> 1;
        const int q   = (id & 1) << 2;
        const float4 v = *(const float4*)(pred + (img << 16) + (row << 8) + j0 + q);
        sp[row][q]     = v.x;  sp[row][q + 1] = v.y;
        sp[row][q + 2] = v.z;  sp[row][q + 3] = v.w;
    }

    // ---------- per-image 32-block barrier ----------
    __syncthreads();                   // all phase-A stores drained pre-barrier
    if (t == 0) {
        __threadfence();               // release (agent scope)
        atomicAdd(&syncw[img << 4], 1u);
        while (__hip_atomic_load(&syncw[img << 4], __ATOMIC_RELAXED,
                                 __HIP_MEMORY_SCOPE_AGENT) < SLICES) {
            __builtin_amdgcn_s_sleep(2);
        }
        __threadfence();               // acquire (invalidate stale lines)
    }
    __syncthreads();

    // ---------- stage f tile ----------
    bool myne = false;
#pragma unroll
    for (int s = 0; s < 2; ++s) {
        const int id  = t + (s << 8);
        const int row = id >> 1;
        const int q   = (id & 1) << 2;
        const float4 v = *(const float4*)(fbuf + (img << 16) + (row << 8) + j0 + q);
        sf[row][q]     = v.x;  sf[row][q + 1] = v.y;
        sf[row][q + 2] = v.z;  sf[row][q + 3] = v.w;
        myne = myne || (v.x > CAPTHR) || (v.y > CAPTHR) ||
                       (v.z > CAPTHR) || (v.w > CAPTHR);
    }
    if (myne) nonempty = 1;            // benign race, all write 1
    __syncthreads();
    const int flag = nonempty;         // exact: mask.sum() != 0

    // ---------- phase B: window-bounded exact min-plus ----------
    const int c  = t & 7;              // own column within tile
    const int r0 = (t >> 3) << 3;      // own 8-row band
    double acc = 0.0;
#pragma unroll
    for (int ii = 0; ii < 8; ++ii) {
        const int i = r0 + ii;
        const float fv = sf[i][c];
        const bool  m  = fv > 0.0f;    // sign(f) = pixel polarity
        const float sgn = m ? 1.0f : -1.0f;
        const float gi = fabsf(fv);
        const int  gii = (int)gi;
        int lo = i - gii; lo = lo > 0 ? lo : 0;
        int hi = i + gii; hi = hi < (H - 1) ? hi : (H - 1);

        float dm = 3.0e38f;
        float dk = (float)(i - lo);
        for (int k = lo; k <= hi; ++k) {
            const float g = fmaxf(sgn * sf[k][c], 0.0f);   // needed polarity
            dm = fminf(dm, g * g + dk * dk);
            dk -= 1.0f;
        }

        float d = m ? sqrtf(dm) : -sqrtf(dm);
        if (!flag) d = 0.0f;
        const float p = sp[i][c];
        const float sig = 1.0f / (1.0f + expf(-p));
        acc += (double)sig * (double)d;
    }

    // wave reduce (double, fixed order), 4 wave sums -> block partial
#pragma unroll
    for (int off = 32; off > 0; off >>= 1) acc += __shfl_down(acc, off, 64);
    if (lane == 0) wsum[wid] = acc;
    __syncthreads();
    if (t == 0) {
        partials[bid] = (wsum[0] + wsum[1]) + (wsum[2] + wsum[3]);
        __threadfence();               // release partial
        const unsigned old = atomicAdd(&syncw[NIMG << 4], 1u);  // ticket (0-init)
        won = (old == (unsigned)(NBLK - 1));
    }
    __syncthreads();

    // ---------- ticket finalize (true last arriver; fixed-order sum) ------
    if (won && t < 64) {
        __threadfence();               // acquire all partials
        double a = 0.0;
#pragma unroll
        for (int s = 0; s < NBLK / 64; ++s) a += partials[t + (s << 6)];
#pragma unroll
        for (int off = 32; off > 0; off >>= 1) a += __shfl_down(a, off, 64);
        if (t == 0) out[0] = (float)(a / (double)(NIMG * NPIX));
    }
}

extern "C" void kernel_launch(void* const* d_in, const int* in_sizes, int n_in,
                              void* d_out, int out_size, void* d_ws, size_t ws_size,
                              hipStream_t stream) {
    const float* pred = (const float*)d_in[0];
    const int*   tgt  = (const int*)d_in[1];
    float* out = (float*)d_out;

    char* ws = (char*)d_ws;
    const size_t fbytes = (size_t)NIMG * NPIX * sizeof(float);   // 6,291,456 B
    float*        fbuf     = (float*)(ws);
    double*       partials = (double*)(ws + fbytes);             // 768 * 8 B
    unsigned int* syncw    = (unsigned int*)(ws + fbytes + NBLK * sizeof(double));

    // 24 per-image barrier counters (64B-padded) + 1 finalize ticket
    hipMemsetAsync(syncw, 0, (NIMG + 1) * 64, stream);
    boundary_fused_kernel<<<NBLK, BLKT, 0, stream>>>(tgt, pred, fbuf,
                                                     partials, syncw, out);
}

// Round 13
// 39.829 us; speedup vs baseline: 2.2758x; 2.2758x over previous
//
#include <hip/hip_runtime.h>
#include <math.h>

#define NIMG 24        // B*C = 8*3
#define H    256
#define W    256
#define NPIX (H * W)
#define NROWS (NIMG * H)
#define CPB  8                    // columns per K2 tile
#define SLICES (W / CPB)          // 32 K2 blocks per image
#define NBLK2 (NIMG * SLICES)     // 768
#define LDP  9                    // padded LDS row stride (floats)
#define BIGI 1000000
#define CAPS 1024                 // int16 sentinel for capped g (=1e6)

// ---------------------------------------------------------------------------
// K1: one WAVE per row (lane owns 4 cols). Ballot-based O(1) row EDT
// (r11-validated bit-exact). Output f encoded int16: +-g for the pixel's
// own polarity (g in [1,256]), sentinel +-1024 for capped g (=1e6) — halves
// the intermediate's dirty/flush bytes (r13 theory). Also zeroes the K2
// sync counters (plain stores; node boundary publishes them) — no extra
// memset node, and fixes r8's poisoned-ticket bug soundly.
// ---------------------------------------------------------------------------
__global__ void edt_rows_kernel(const int* __restrict__ tgt,
                                short* __restrict__ f,
                                unsigned int* __restrict__ syncw) {
    if (blockIdx.x == 0 && threadIdx.x <= NIMG)
        syncw[threadIdx.x << 4] = 0;   // 24 per-image counters + 1 gate (64B apart)

    const int tid  = blockIdx.x * 256 + threadIdx.x;
    const int gw   = tid >> 6;          // global wave id == row id
    const int lane = tid & 63;
    const int img  = gw >> 8;
    const int row  = gw & 255;

    const int4 tv = ((const int4*)(tgt + (img << 16) + (row << 8)))[lane];
    const int c0 = lane << 2;

    // class-change flags (global index 0 has no predecessor -> false)
    const int prevw = __shfl_up(tv.w, 1, 64);
    const bool ch0 = (lane > 0) && ((tv.x != 0) != (prevw != 0));
    const bool ch1 = (tv.y != 0) != (tv.x != 0);
    const bool ch2 = (tv.z != 0) != (tv.y != 0);
    const bool ch3 = (tv.w != 0) != (tv.z != 0);

    const int a0 = ch0 ? c0     : -BIGI;
    const int a1 = ch1 ? c0 + 1 : a0;
    const int a2 = ch2 ? c0 + 2 : a1;
    const int a3 = ch3 ? c0 + 3 : a2;     // lane's last change pos (or -BIGI)
    const int rb3 = ch3 ? c0 + 3 : BIGI;
    const int rb2 = ch2 ? c0 + 2 : rb3;
    const int rb1 = ch1 ? c0 + 1 : rb2;
    const int rb0 = ch0 ? c0     : rb1;   // lane's first change pos (or BIGI)

    const unsigned long long mask = __ballot(ch0 | ch1 | ch2 | ch3);
    const unsigned long long lowm = mask & ((1ULL << lane) - 1ULL);
    const unsigned long long him  = (lane < 63) ? (mask >> (lane + 1)) : 0ULL;

    const int plane = 63 - __builtin_clzll(lowm | 1ULL);
    const int sh_a  = __shfl(a3, plane & 63, 64);
    const int ex    = (lowm != 0ULL) ? sh_a : -BIGI;   // last change < c0

    const int qlane = lane + 1 +
        (int)__builtin_ctzll(him | 0x8000000000000000ULL);
    const int sh_r  = __shfl(rb0, qlane & 63, 64);
    const int exr   = (him != 0ULL) ? sh_r : BIGI;     // first change > c3

    const int s0 = (ex > a0) ? ex : a0;
    const int s1 = (ex > a1) ? ex : a1;
    const int s2 = (ex > a2) ? ex : a2;
    const int s3 = (ex > a3) ? ex : a3;
    const int n0 = (rb1 < exr) ? rb1 : exr;
    const int n1 = (rb2 < exr) ? rb2 : exr;
    const int n2 = (rb3 < exr) ? rb3 : exr;
    const int n3 = exr;

    auto gcalc = [](int c, int ss, int nn) -> int {
        int dp = c - ss + 1;
        int dn = nn - c;
        int g = dp < dn ? dp : dn;
        return (g < BIGI) ? g : CAPS;      // encode cap as sentinel 1024
    };
    const int g0 = gcalc(c0,     s0, n0);
    const int g1 = gcalc(c0 + 1, s1, n1);
    const int g2 = gcalc(c0 + 2, s2, n2);
    const int g3 = gcalc(c0 + 3, s3, n3);

    short4 o;
    o.x = (short)((tv.x != 0) ? g0 : -g0);
    o.y = (short)((tv.y != 0) ? g1 : -g1);
    o.z = (short)((tv.z != 0) ? g2 : -g2);
    o.w = (short)((tv.w != 0) ? g3 : -g3);
    ((short4*)(f + (img << 16) + (row << 8)))[lane] = o;
}

// ---------------------------------------------------------------------------
// K2: block = (img, 8-col group), 768 blocks x 256 thr. Stage = 1 int4
// (8 shorts) per thread, decoded (sentinel +-1024 -> +-1e6f) into padded
// float LDS tile — same exact fp32 values as r11 (capped terms round
// identically: 1e12 + small). Window-bounded exact min-plus (minimizer
// satisfies |i-k| <= g[i]; finite terms exact fp32 ints -> bitwise equal
// to reference). Empty-mask flag: all staged shorts == -1024.
// Fused finalize via HIERARCHICAL ticket (r3 lesson: no same-line atomic
// pileups — 32 adds on each of 24 distinct lines, then 24 adds on a gate
// line; counters zeroed by K1, so last-arrival detection is sound, fixing
// r8). Winner reduces 768 partials in fixed order -> deterministic.
// NO producer->consumer in-kernel sync (r7+r12 lesson: fence/spin barriers
// cost ~55-60us on this chip; only consumer-side tickets are viable).
// ---------------------------------------------------------------------------
__global__ __launch_bounds__(256)
void edt_cols_kernel(const short* __restrict__ f,
                     const float* __restrict__ pred,
                     double* __restrict__ partials,
                     unsigned int* __restrict__ syncw,
                     float* __restrict__ out) {
    const int bid  = blockIdx.x;          // img*32 + grp
    const int img  = bid >> 5;
    const int j0   = (bid & 31) << 3;
    const int t    = threadIdx.x;
    const int lane = t & 63;
    const int wid  = t >> 6;

    __shared__ float sf[H][LDP];          // 9.2 KB decoded f tile
    __shared__ double wsum[4];
    __shared__ int nonempty, won;
    if (t == 0) nonempty = 0;
    __syncthreads();

    // stage: thread t owns row t (8 shorts = one 16B load)
    {
        const int4 rv = *(const int4*)(f + (img << 16) + (t << 8) + j0);
        const short* sv = (const short*)&rv;
        bool ne = false;
#pragma unroll
        for (int j = 0; j < 8; ++j) {
            const int v = sv[j];
            ne = ne || (v != -CAPS);
            float g = (float)v;
            if (v == CAPS)  g =  1.0e6f;
            if (v == -CAPS) g = -1.0e6f;
            sf[t][j] = g;
        }
        if (ne) nonempty = 1;             // benign race, all write 1
    }
    __syncthreads();
    const int flag = nonempty;            // exact: mask.sum() != 0

    // phase B: window-bounded exact min-plus
    const int c  = t & 7;                 // own column within tile
    const int r0 = (t >> 3) << 3;         // own 8-row band
    double acc = 0.0;
#pragma unroll
    for (int ii = 0; ii < 8; ++ii) {
        const int i = r0 + ii;
        const float fv = sf[i][c];
        const bool  m  = fv > 0.0f;       // sign(f) = pixel polarity
        const float sgn = m ? 1.0f : -1.0f;
        const float gi = fabsf(fv);
        const int  gii = (int)gi;
        int lo = i - gii; lo = lo > 0 ? lo : 0;
        int hi = i + gii; hi = hi < (H - 1) ? hi : (H - 1);

        float dm = 3.0e38f;
        float dk = (float)(i - lo);
        for (int k = lo; k <= hi; ++k) {
            const float g = fmaxf(sgn * sf[k][c], 0.0f);  // needed polarity
            dm = fminf(dm, g * g + dk * dk);
            dk -= 1.0f;
        }

        float d = m ? sqrtf(dm) : -sqrtf(dm);
        if (!flag) d = 0.0f;
        const float p = pred[(img << 16) + (i << 8) + j0 + c];
        const float sig = 1.0f / (1.0f + expf(-p));
        acc += (double)sig * (double)d;
    }

    // wave reduce (double, fixed order), 4 wave sums -> block partial
#pragma unroll
    for (int off = 32; off > 0; off >>= 1) acc += __shfl_down(acc, off, 64);
    if (lane == 0) wsum[wid] = acc;
    __syncthreads();
    if (t == 0) {
        partials[bid] = (wsum[0] + wsum[1]) + (wsum[2] + wsum[3]);
        __threadfence();                  // release partial
        int w = 0;
        const unsigned o1 = atomicAdd(&syncw[img << 4], 1u);
        if (o1 == (unsigned)(SLICES - 1)) {
            const unsigned o2 = atomicAdd(&syncw[NIMG << 4], 1u);
            w = (o2 == (unsigned)(NIMG - 1));
        }
        won = w;
    }
    __syncthreads();

    // true last arriver reduces all partials in fixed order
    if (won && t < 64) {
        __threadfence();                  // acquire all partials
        double a = 0.0;
#pragma unroll
        for (int s = 0; s < NBLK2 / 64; ++s) a += partials[t + (s << 6)];
#pragma unroll
        for (int off = 32; off > 0; off >>= 1) a += __shfl_down(a, off, 64);
        if (t == 0) out[0] = (float)(a / (double)(NIMG * NPIX));
    }
}

extern "C" void kernel_launch(void* const* d_in, const int* in_sizes, int n_in,
                              void* d_out, int out_size, void* d_ws, size_t ws_size,
                              hipStream_t stream) {
    const float* pred = (const float*)d_in[0];
    const int*   tgt  = (const int*)d_in[1];
    float* out = (float*)d_out;

    char* ws = (char*)d_ws;
    const size_t fbytes = (size_t)NIMG * NPIX * sizeof(short);   // 3,145,728 B
    short*        fbuf     = (short*)(ws);
    double*       partials = (double*)(ws + fbytes);             // 768 * 8 B
    unsigned int* syncw    = (unsigned int*)(ws + fbytes + NBLK2 * sizeof(double));

    edt_rows_kernel<<<NROWS / 4, 256, 0, stream>>>(tgt, fbuf, syncw);
    edt_cols_kernel<<<NBLK2, 256, 0, stream>>>(fbuf, pred, partials, syncw, out);
}